// Round 5
// baseline (64.760 us; speedup 1.0000x reference)
//
#include <hip/hip_runtime.h>

// Problem constants (from reference): B=128, T=4096, N=16, D=3
#define BB 128
#define TT 4096
#define NN 16
#define DD 3
#define TPB 256
#define GROUPS (TPB/NN)              // 16 lane-groups per block
#define SPB (2*GROUPS)               // 32 slabs per block (2 per group, ILP)
#define NBLK ((BB*TT)/SPB)           // 16384 blocks

// 12-byte aggregate, 4-B aligned -> compiler emits global_load_dwordx3
struct f3 { float a, b, c; };

// Lane-parallel analytic inverse of the Jacobi matrix (no LDS, no barriers):
//   c_k = m_k / M_k (prefix sum of masses), c_0 := 1
//   r_k = x0 + x_k - sum_{i=k}^{N-1} c_i x_i      (uniform for all k with c_0=1)
// 16 lanes per slab (one k per lane, 3 d-components per lane).
// Each group handles TWO slabs, all 4 loads issued before any scan (MLP).
__global__ __launch_bounds__(TPB) void jacobi_to_cartesian_kernel(
    const float* __restrict__ m,
    const float* __restrict__ qj,
    const float* __restrict__ vj,
    float* __restrict__ outq,
    float* __restrict__ outv)
{
    const int t = threadIdx.x;
    const int l = t & (NN - 1);                       // k index within slab
    const size_t slab0 = (size_t)blockIdx.x * SPB + (t >> 4);
    const size_t slab1 = slab0 + GROUPS;
    const int b = (int)(slab0 >> 12);                 // slab / TT; same for slab1 (32 | 4096)

    // c_l = m_l / M_l via width-16 inclusive prefix scan
    const float mk = m[b * NN + l];
    float M = mk;
    #pragma unroll
    for (int d = 1; d < NN; d <<= 1) {
        float tmp = __shfl_up(M, d, NN);
        if (l >= d) M += tmp;
    }
    const float c = (l == 0) ? 1.0f : mk / M;

    const size_t base0 = slab0 * (size_t)(NN * DD) + (size_t)l * DD;
    const size_t base1 = slab1 * (size_t)(NN * DD) + (size_t)l * DD;

    // Issue ALL FOUR loads before any dependent compute (memory-level parallelism)
    const f3 xq0 = *(const f3*)(qj + base0);
    const f3 xq1 = *(const f3*)(qj + base1);
    const f3 xv0 = *(const f3*)(vj + base0);
    const f3 xv1 = *(const f3*)(vj + base1);

    float y[4][3] = {
        { c * xq0.a, c * xq0.b, c * xq0.c },
        { c * xq1.a, c * xq1.b, c * xq1.c },
        { c * xv0.a, c * xv0.b, c * xv0.c },
        { c * xv1.a, c * xv1.b, c * xv1.c },
    };

    // Suffix-scan all 12 values jointly within each 16-lane group
    #pragma unroll
    for (int d = 1; d < NN; d <<= 1) {
        const bool take = (l + d < NN);
        #pragma unroll
        for (int s = 0; s < 4; ++s) {
            float t0 = __shfl_down(y[s][0], d, NN);
            float t1 = __shfl_down(y[s][1], d, NN);
            float t2 = __shfl_down(y[s][2], d, NN);
            if (take) { y[s][0] += t0; y[s][1] += t1; y[s][2] += t2; }
        }
    }

    const f3* xs[4] = { &xq0, &xq1, &xv0, &xv1 };
    float* dsts[4] = { outq + base0, outq + base1, outv + base0, outv + base1 };

    #pragma unroll
    for (int s = 0; s < 4; ++s) {
        const float x00 = __shfl(xs[s]->a, 0, NN);   // x0 broadcast (COM coordinate)
        const float x01 = __shfl(xs[s]->b, 0, NN);
        const float x02 = __shfl(xs[s]->c, 0, NN);
        __builtin_nontemporal_store(x00 + xs[s]->a - y[s][0], dsts[s] + 0);
        __builtin_nontemporal_store(x01 + xs[s]->b - y[s][1], dsts[s] + 1);
        __builtin_nontemporal_store(x02 + xs[s]->c - y[s][2], dsts[s] + 2);
    }
}

extern "C" void kernel_launch(void* const* d_in, const int* in_sizes, int n_in,
                              void* d_out, int out_size, void* d_ws, size_t ws_size,
                              hipStream_t stream) {
    const float* m  = (const float*)d_in[0];
    const float* qj = (const float*)d_in[1];
    const float* vj = (const float*)d_in[2];

    float* outq = (float*)d_out;
    float* outv = outq + (size_t)BB * TT * NN * DD;

    jacobi_to_cartesian_kernel<<<NBLK, TPB, 0, stream>>>(m, qj, vj, outq, outv);
}